// Round 21
// baseline (455.594 us; speedup 1.0000x reference)
//
#include <hip/hip_runtime.h>
#include <hip/hip_bf16.h>
#include <cstddef>
#include <cstdint>

#define DEV_INLINE __device__ __forceinline__
#define AS1 __attribute__((address_space(1)))
#define AS3 __attribute__((address_space(3)))

typedef __attribute__((ext_vector_type(8))) short short8;
typedef __attribute__((ext_vector_type(4))) float f32x4;
typedef __attribute__((ext_vector_type(2))) float f32x2;
typedef __attribute__((ext_vector_type(4))) unsigned short us4;

DEV_INLINE unsigned short f2bf(float f) {
  uint32_t u = __builtin_bit_cast(uint32_t, f);
  uint32_t r = (u + 0x7fffu + ((u >> 16) & 1u)) >> 16;
  return (unsigned short)r;
}
DEV_INLINE float bf2f(unsigned short u) {
  return __builtin_bit_cast(float, (uint32_t)u << 16);
}

DEV_INLINE void gl_lds16(const float* g, float* l) {
  __builtin_amdgcn_global_load_lds((AS1 void*)const_cast<float*>(g),
                                   (AS3 void*)l, 16, 0, 0);
}

// Problem constants: BS=2, F=8, C=64, H=128, W=128, HEADS=4
__device__ __constant__ int c_cs[15] = {0,8,16,32,48,65,66,67,75,83,99,115,132,133,134};
__device__ __constant__ int c_row[134] = {
  0,1,2,3,4,5,6,7,
  8,9,10,11,12,13,14,15,
  0,1,2,3,4,5,6,7,8,9,10,11,12,13,14,15,
  0,1,2,3,4,5,6,7,8,9,10,11,12,13,14,15,
  0,1,2,3,4,5,6,7,8,9,10,11,12,13,14,15,16,
  16,
  17,
  18,19,20,21,22,23,24,25,
  26,27,28,29,30,31,32,33,
  18,19,20,21,22,23,24,25,26,27,28,29,30,31,32,33,
  18,19,20,21,22,23,24,25,26,27,28,29,30,31,32,33,
  18,19,20,21,22,23,24,25,26,27,28,29,30,31,32,33,34,
  34,
  35
};
__device__ __constant__ int c_col[134] = {
  0,0,0,0,0,0,0,0,
  1,1,1,1,1,1,1,1,
  2,2,2,2,2,2,2,2,2,2,2,2,2,2,2,2,
  3,3,3,3,3,3,3,3,3,3,3,3,3,3,3,3,
  4,4,4,4,4,4,4,4,4,4,4,4,4,4,4,4,4,
  5,
  6,
  7,7,7,7,7,7,7,7,
  8,8,8,8,8,8,8,8,
  9,9,9,9,9,9,9,9,9,9,9,9,9,9,9,9,
  10,10,10,10,10,10,10,10,10,10,10,10,10,10,10,10,
  11,11,11,11,11,11,11,11,11,11,11,11,11,11,11,11,11,
  12,
  13
};

// LDS chunk offset for prep: 16B-aligned, bank-spreading (σ pattern -> 2-way reads)
DEV_INLINE int pofs(int ci) { return 260 * ci + 4 * (ci >> 3); }

// ---------------- fused: batched input prep (both branches) + all weight transforms --
// prep blocks 0..2047 (1024/branch): (n, y0=2y') tile, 64 ci x 2 y x 128 x.
// Each DMA reads ONE ci's contiguous 1KB (2 y-rows). blocks >= 2048: weight transform.
__global__ __launch_bounds__(512) void k_prep_all(
    const float* __restrict__ mf, const float* __restrict__ mp,
    const float* __restrict__ vf, const float* __restrict__ vp,
    unsigned short* __restrict__ p0nm, unsigned short* __restrict__ p0nv,
    const float* __restrict__ cv1w, const float* __restrict__ dc1w,
    const float* __restrict__ cv2w, const float* __restrict__ dc2w,
    const float* __restrict__ tc1w, const float* __restrict__ tc2w,
    unsigned short* __restrict__ wtb) {
  __shared__ float sbuf[16664];   // pofs(63)+256 = 16408+256
  int bid = blockIdx.x;
  int t = threadIdx.x;
  if (bid >= 2048) {
    // weight transform: wT[tap][co][ci] bf16
    int idx = (bid - 2048) * 512 + t;
    if (idx >= 1105920) return;
    const float* src; int off, lci, lco; bool tra;
    if (idx < 73728)        { src = cv1w; off = 0;       lci = 6; lco = 7; tra = false; }
    else if (idx < 147456)  { src = dc1w; off = 73728;   lci = 6; lco = 7; tra = false; }
    else if (idx < 442368)  { src = cv2w; off = 147456;  lci = 7; lco = 8; tra = false; }
    else if (idx < 737280)  { src = dc2w; off = 442368;  lci = 7; lco = 8; tra = false; }
    else if (idx < 1032192) { src = tc1w; off = 737280;  lci = 8; lco = 7; tra = true;  }
    else                    { src = tc2w; off = 1032192; lci = 7; lco = 6; tra = true;  }
    int l = idx - off;
    int ci = l & ((1 << lci) - 1);
    int r = l >> lci;
    int co = r & ((1 << lco) - 1);
    int tap = r >> lco;
    size_t si = tra ? (((size_t)ci << lco) + co) * 9 + tap
                    : (((size_t)co << lci) + ci) * 9 + tap;
    wtb[idx] = f2bf(src[si]);
    return;
  }
  // prep: (a+b) NCHW fp32 -> NHWC bf16, 1KB contiguous DMA reads (2 y-rows per ci)
  const float* a = (bid < 1024) ? mf : vf;
  const float* b = (bid < 1024) ? mp : vp;
  unsigned short* o = (bid < 1024) ? p0nm : p0nv;
  int b2 = bid & 1023;
  int yb = b2 & 63, n = b2 >> 6;
  int y0 = yb * 2;
  int w = t >> 6, lane = t & 63;
  const size_t srcbase = ((size_t)n * 64) * 16384 + (size_t)y0 * 128 + lane * 4;
  // phase A: stage a (each wave DMAs 8 ci chunks; chunk = 256 contiguous floats)
#pragma unroll
  for (int k = 0; k < 8; ++k) {
    int ci = w * 8 + k;
    gl_lds16(a + srcbase + (size_t)ci * 16384, &sbuf[pofs(ci)]);
  }
  __syncthreads();
  auto rd = [&](int ci, int yy, int x) {
    return sbuf[pofs(ci) + yy * 128 + x];
  };
  // park a-values in registers: per (it, yy): 8 ci at (yy, x)
  float av[2][2][8];
#pragma unroll
  for (int it = 0; it < 2; ++it) {
    int i = t + it * 512;
    int x = i >> 3, cq = i & 7;
#pragma unroll
    for (int yy = 0; yy < 2; ++yy)
#pragma unroll
      for (int j = 0; j < 8; ++j) av[it][yy][j] = rd(cq * 8 + j, yy, x);
  }
  __syncthreads();
  // phase B: stage b
#pragma unroll
  for (int k = 0; k < 8; ++k) {
    int ci = w * 8 + k;
    gl_lds16(b + srcbase + (size_t)ci * 16384, &sbuf[pofs(ci)]);
  }
  __syncthreads();
#pragma unroll
  for (int it = 0; it < 2; ++it) {
    int i = t + it * 512;
    int x = i >> 3, cq = i & 7;
#pragma unroll
    for (int yy = 0; yy < 2; ++yy) {
      unsigned int* op = (unsigned int*)(o + (((size_t)n * 128 + y0 + yy) * 128) * 64);
      uint4 v;
      unsigned int vv[4];
#pragma unroll
      for (int jj = 0; jj < 4; ++jj) {
        unsigned int lo = f2bf(av[it][yy][2 * jj]     + rd(cq * 8 + 2 * jj, yy, x));
        unsigned int hi = f2bf(av[it][yy][2 * jj + 1] + rd(cq * 8 + 2 * jj + 1, yy, x));
        vv[jj] = lo | (hi << 16);
      }
      v.x = vv[0]; v.y = vv[1]; v.z = vv[2]; v.w = vv[3];
      *reinterpret_cast<uint4*>(op + x * 32 + cq * 4) = v;
    }
  }
}

// ---------------- Conv2d k3 s2 p1 + bias + ReLU via bf16 MFMA (branch-batched) -------
template<int CI, int CO, int HO, int WO, int ROUT, bool SPLIT_IN>
__global__ __launch_bounds__(512, 3) void k_conv_mfma_b(
    const unsigned short* __restrict__ in0, const unsigned short* __restrict__ in1,
    const unsigned short* __restrict__ wT0, const unsigned short* __restrict__ wT1,
    const float* __restrict__ b0, const float* __restrict__ b1,
    unsigned short* __restrict__ outn) {
  constexpr int HIN = HO * 2, WIN = WO * 2;
  constexpr int XHP = WO + 2;
  constexpr int R = 2 * ROUT + 1;
  constexpr int NPOS = R * 2 * XHP;
  constexpr int NCH = NPOS * 4;
  constexpr int NCS = CI / 32;
  constexpr int KIT = (NCH + 511) / 512;
  constexpr int CB = CO / 128;
  constexpr int OB = HO / ROUT;
  __shared__ short8 sIn[NPOS * 5];
  int bid = blockIdx.x;
  int cb = bid % CB; bid /= CB;
  int oyb = bid % OB; int n = bid / OB;     // n 0..31
  int br = n >> 4;
  const unsigned short* in = SPLIT_IN ? (br ? in1 : in0) : in0;
  const unsigned short* wT = br ? wT1 : wT0;
  const float* bias = br ? b1 : b0;
  int ni = SPLIT_IN ? (n & 15) : n;
  int tid = threadIdx.x;
  int wid = tid >> 6, lane = tid & 63;
  int wm = wid >> 1, wn = wid & 1;
  int llo = lane & 15, lhi = lane >> 4;
  f32x4 acc[2][2] = {};
  const int iy0 = oyb * (2 * ROUT) - 1;
  short8 rv[KIT];
  auto loadr = [&](int cs) {
#pragma unroll
    for (int k = 0; k < KIT; ++k) {
      int i = tid + k * 512;
      short8 v = {};
      if (i < NCH) {
        int c = i & 3, q = i >> 2;
        int xh = q % XHP; int q2 = q / XHP;
        int p = q2 & 1, l = q2 >> 1;
        int x = 2 * xh + p - 1;
        int iy = iy0 + l;
        if (x >= 0 && x < WIN && iy >= 0 && iy < HIN)
          v = *reinterpret_cast<const short8*>(in + ((((size_t)ni * HIN + iy) * WIN + x) * CI + cs * 32 + c * 8));
      }
      rv[k] = v;
    }
  };
  auto writes = [&]() {
#pragma unroll
    for (int k = 0; k < KIT; ++k) {
      int i = tid + k * 512;
      if (i < NCH) sIn[(i >> 2) * 5 + (i & 3)] = rv[k];
    }
  };
  loadr(0);
  for (int cs = 0; cs < NCS; ++cs) {
    writes();
    __syncthreads();
    if (cs + 1 < NCS) loadr(cs + 1);
    short8 afr9[9][2];
#pragma unroll
    for (int tap = 0; tap < 9; ++tap)
#pragma unroll
      for (int m = 0; m < 2; ++m) {
        int co = cb * 128 + wm * 32 + m * 16 + llo;
        afr9[tap][m] = *reinterpret_cast<const short8*>(wT + (((size_t)tap * CO + co) * CI + cs * 32 + lhi * 8));
      }
#pragma unroll
    for (int tap = 0; tap < 9; ++tap) {
      const int ky = tap / 3, kx = tap % 3;
      short8 bfr[2];
#pragma unroll
      for (int n2 = 0; n2 < 2; ++n2) {
        int pix = wn * 32 + n2 * 16 + llo;
        int oyl = (ROUT == 2) ? (pix >> 5) : 0;
        int ox = pix - oyl * WO;
        int lrow = 2 * oyl + ky;
        int pos = (lrow * 2 + (kx & 1)) * XHP + ox + (kx >> 1);
        bfr[n2] = sIn[pos * 5 + lhi];
      }
#pragma unroll
      for (int m = 0; m < 2; ++m)
#pragma unroll
        for (int n2 = 0; n2 < 2; ++n2)
          acc[m][n2] = __builtin_amdgcn_mfma_f32_16x16x32_bf16(afr9[tap][m], bfr[n2], acc[m][n2], 0, 0, 0);
    }
    __syncthreads();
  }
#pragma unroll
  for (int m = 0; m < 2; ++m) {
    int co0 = cb * 128 + wm * 32 + m * 16 + lhi * 4;
    f32x4 bv = *reinterpret_cast<const f32x4*>(bias + co0);
#pragma unroll
    for (int n2 = 0; n2 < 2; ++n2) {
      int pix = wn * 32 + n2 * 16 + llo;
      int oyl = (ROUT == 2) ? (pix >> 5) : 0;
      int ox = pix - oyl * WO;
      int oy = oyb * ROUT + oyl;
      us4 pk;
      pk[0] = f2bf(fmaxf(acc[m][n2][0] + bv[0], 0.f));
      pk[1] = f2bf(fmaxf(acc[m][n2][1] + bv[1], 0.f));
      pk[2] = f2bf(fmaxf(acc[m][n2][2] + bv[2], 0.f));
      pk[3] = f2bf(fmaxf(acc[m][n2][3] + bv[3], 0.f));
      *reinterpret_cast<us4*>(outn + ((((size_t)n * HO + oy) * WO + ox) * CO + co0)) = pk;
    }
  }
}

// ---------------- ConvTranspose2d k3 s2 p1 op1 via bf16 MFMA (round-14 shape) --------
template<int CI, int CO, int Hi, int Wi, int QR, bool OBF, bool GADD>
__global__ __launch_bounds__(256, 3) void k_deconv_mfma(
    const unsigned short* __restrict__ in,
    const unsigned short* __restrict__ wT,
    const float* __restrict__ bias,
    const unsigned short* __restrict__ resn,
    const float* __restrict__ gsrc,
    unsigned short* __restrict__ outn,
    float* __restrict__ outc) {
  constexpr int QC = 64 / QR;
  constexpr int WP = Wi + 1;
  constexpr int NPOS = (QR + 1) * WP;
  constexpr int NCH = NPOS * 4;
  constexpr int NCS = CI / 32;
  constexpr int KIT = (NCH + 255) / 256;
  constexpr int CB = CO / 64;
  constexpr int OB = Hi / QR;
  constexpr int Ho = Hi * 2, Wo = Wi * 2;
  __shared__ short8 sIn[NPOS * 5];
  int bid = blockIdx.x;
  int cb = bid % CB; bid /= CB;
  int oyb = bid % OB; int n = bid / OB;
  int tid = threadIdx.x;
  int wid = tid >> 6, lane = tid & 63;
  int wm = wid >> 1, wn = wid & 1;
  int llo = lane & 15, lhi = lane >> 4;
  int qy0 = oyb * QR;
  const float* g = nullptr;
  if constexpr (GADD) g = gsrc + ((size_t)((n >> 3) * 18 + (n & 7))) * 256;
  f32x4 acc[4][2][2] = {};
  constexpr int tap_p[9] = {3,2,3,1,0,1,3,2,3};
  constexpr int tap_b[9] = {3,2,2,1,0,0,1,0,0};
  short8 rv[KIT];
  auto loadr = [&](int cs) {
#pragma unroll
    for (int k = 0; k < KIT; ++k) {
      int i = tid + k * 256;
      short8 v = {};
      if (i < NCH) {
        int c = i & 3, q = i >> 2;
        int x = q % WP, l = q / WP;
        int iy = qy0 + l;
        if (x < Wi && iy < Hi) {
          v = *reinterpret_cast<const short8*>(in + (((size_t)(n * Hi + iy) * Wi + x) * CI + cs * 32 + c * 8));
          if constexpr (GADD) {
#pragma unroll
            for (int j = 0; j < 8; ++j) {
              float fv = bf2f((unsigned short)v[j]) + g[cs * 32 + c * 8 + j];
              v[j] = (short)f2bf(fv);
            }
          }
        }
      }
      rv[k] = v;
    }
  };
  auto writes = [&]() {
#pragma unroll
    for (int k = 0; k < KIT; ++k) {
      int i = tid + k * 256;
      if (i < NCH) sIn[(i >> 2) * 5 + (i & 3)] = rv[k];
    }
  };
  loadr(0);
  for (int cs = 0; cs < NCS; ++cs) {
    writes();
    __syncthreads();
    if (cs + 1 < NCS) loadr(cs + 1);
    short8 bfr[2][4];
#pragma unroll
    for (int n2 = 0; n2 < 2; ++n2) {
      int pix = wn * 32 + n2 * 16 + llo;
      int qyl = pix / QC, qx = pix % QC;
#pragma unroll
      for (int bs = 0; bs < 4; ++bs) {
        int pos = (qyl + (bs >> 1)) * WP + qx + (bs & 1);
        bfr[n2][bs] = sIn[pos * 5 + lhi];
      }
    }
#pragma unroll
    for (int m = 0; m < 2; ++m) {
      short8 afr9[9];
#pragma unroll
      for (int tap = 0; tap < 9; ++tap) {
        int co = cb * 64 + wm * 32 + m * 16 + llo;
        afr9[tap] = *reinterpret_cast<const short8*>(wT + (((size_t)tap * CO + co) * CI + cs * 32 + lhi * 8));
      }
#pragma unroll
      for (int tap = 0; tap < 9; ++tap)
#pragma unroll
        for (int n2 = 0; n2 < 2; ++n2)
          acc[tap_p[tap]][m][n2] = __builtin_amdgcn_mfma_f32_16x16x32_bf16(
              afr9[tap], bfr[n2][tap_b[tap]], acc[tap_p[tap]][m][n2], 0, 0, 0);
    }
    __syncthreads();
  }
#pragma unroll
  for (int m = 0; m < 2; ++m) {
    int co0 = cb * 64 + wm * 32 + m * 16 + lhi * 4;
    f32x4 bv = *reinterpret_cast<const f32x4*>(bias + co0);
#pragma unroll
    for (int n2 = 0; n2 < 2; ++n2) {
      int pix = wn * 32 + n2 * 16 + llo;
      int qyl = pix / QC, qx = pix % QC;
      int qy = qy0 + qyl;
      if constexpr (OBF) {
#pragma unroll
        for (int p = 0; p < 4; ++p) {
          int oy = 2 * qy + (p >> 1);
          int ox = 2 * qx + (p & 1);
          size_t ad = ((size_t)(n * Ho + oy) * Wo + ox) * CO + co0;
          us4 r = *reinterpret_cast<const us4*>(resn + ad);
          us4 pk;
#pragma unroll
          for (int c = 0; c < 4; ++c)
            pk[c] = f2bf(bf2f(r[c]) + fmaxf(acc[p][m][n2][c] + bv[c], 0.f));
          *reinterpret_cast<us4*>(outn + ad) = pk;
        }
      } else {
        int qx2 = 2 * qx;
#pragma unroll
        for (int dy = 0; dy < 2; ++dy) {
          int oy = 2 * qy + dy;
          size_t rb = ((size_t)(n * Ho + oy) * Wo + qx2) * CO + co0;
          us4 r0 = *reinterpret_cast<const us4*>(resn + rb);
          us4 r1 = *reinterpret_cast<const us4*>(resn + rb + CO);
#pragma unroll
          for (int c = 0; c < 4; ++c) {
            f32x2 st;
            st[0] = bf2f(r0[c]) + fmaxf(acc[dy * 2][m][n2][c] + bv[c], 0.f);
            st[1] = bf2f(r1[c]) + fmaxf(acc[dy * 2 + 1][m][n2][c] + bv[c], 0.f);
            __builtin_nontemporal_store(st,
                reinterpret_cast<f32x2*>(outc + ((size_t)(n * CO + co0 + c) * Ho + oy) * Wo + qx2));
          }
        }
      }
    }
  }
}

// ---------------- stage 1: partial spatial max, batched over 32 n ----------
__global__ __launch_bounds__(256) void k_max_part(const unsigned short* __restrict__ x,
                                                  float* __restrict__ pmax) {
  int n = blockIdx.x >> 3, pg = blockIdx.x & 7;
  int t = threadIdx.x;
  int c8 = t & 31;
  int ps = t >> 5;
  const unsigned short* base = x + (size_t)n * 262144 + (size_t)pg * 32768 + (size_t)c8 * 8;
  float m[8];
#pragma unroll
  for (int j = 0; j < 8; ++j) m[j] = -1e30f;
  for (int p = ps * 16; p < ps * 16 + 16; ++p) {
    short8 v = *reinterpret_cast<const short8*>(base + (size_t)p * 256);
#pragma unroll
    for (int j = 0; j < 8; ++j) m[j] = fmaxf(m[j], bf2f((unsigned short)v[j]));
  }
  __shared__ float sred[8][264];
#pragma unroll
  for (int j = 0; j < 8; ++j) sred[ps][c8 * 8 + j] = m[j];
  __syncthreads();
  float mm = sred[0][t];
#pragma unroll
  for (int g = 1; g < 8; ++g) mm = fmaxf(mm, sred[g][t]);
  pmax[((size_t)n * 8 + pg) * 256 + t] = mm;
}

// ---------------- stage 2: combine partials + LayerNorm, batched ----------
__global__ __launch_bounds__(256) void k_ln(const float* __restrict__ pmax,
                                            float* __restrict__ out) {
  int n = blockIdx.x, ch = threadIdx.x;
  float m = -1e30f;
#pragma unroll
  for (int g = 0; g < 8; ++g)
    m = fmaxf(m, pmax[((size_t)n * 8 + g) * 256 + ch]);
  __shared__ float r1[256], r2[256];
  r1[ch] = m; __syncthreads();
  for (int s = 128; s > 0; s >>= 1) { if (ch < s) r1[ch] += r1[ch + s]; __syncthreads(); }
  float mu = r1[0] * (1.f / 256.f);
  float d = m - mu;
  r2[ch] = d * d; __syncthreads();
  for (int s = 128; s > 0; s >>= 1) { if (ch < s) r2[ch] += r2[ch + s]; __syncthreads(); }
  out[(size_t)n * 256 + ch] = d * rsqrtf(r2[0] * (1.f / 256.f) + 1e-5f);
}

// ---------------- build node features (text pool fused in) ----------------
__global__ void k_build_x(const float* __restrict__ tf, const float* __restrict__ tp,
                          const float* __restrict__ nb,
                          float* __restrict__ tn, float* __restrict__ x0) {
  int b = blockIdx.x, ch = threadIdx.x;
  int c4 = ch >> 2, j = ch & 3;
  const float* p = tf + ((size_t)b * 64 + c4) * 16 + j * 4;
  const float* q = tp + ((size_t)b * 64 + c4) * 16 + j * 4;
  float tv = p[0] + q[0];
  tv = fmaxf(tv, p[1] + q[1]);
  tv = fmaxf(tv, p[2] + q[2]);
  tv = fmaxf(tv, p[3] + q[3]);
  tn[(size_t)b * 256 + ch] = tv;
  const float* dn = nb;
  const float* vn = nb + 16 * 256;
  float s = 0.f;
  for (int f = 0; f < 8; ++f) {
    float vv = vn[((size_t)b * 8 + f) * 256 + ch];
    float dd = dn[((size_t)b * 8 + f) * 256 + ch];
    s += vv + dd;
    x0[((size_t)b * 18 + f) * 256 + ch] = vv;
    x0[((size_t)b * 18 + 8 + f) * 256 + ch] = dd;
  }
  x0[((size_t)b * 18 + 16) * 256 + ch] = tv;
  x0[((size_t)b * 18 + 17) * 256 + ch] = tv + s * (1.f / 8.f);
}

// ---------------- GNN linear ----------------
__global__ __launch_bounds__(256) void k_gnn_lin(
    const float* __restrict__ x, const float* __restrict__ ea,
    const float* __restrict__ w, float* __restrict__ y, int K, int M) {
  int chunks = M >> 8;
  int r = blockIdx.x / chunks;
  int ob = (blockIdx.x % chunks) * 256 + threadIdx.x;
  const float* src = (r < 36) ? (x + (size_t)r * K) : (ea + (size_t)(r - 36) * K);
  __shared__ __align__(16) float sxr[512];
  for (int k = threadIdx.x; k < K; k += 256) sxr[k] = src[k];
  __syncthreads();
  const float4* w4 = reinterpret_cast<const float4*>(w + (size_t)ob * K);
  const float4* x4 = reinterpret_cast<const float4*>(sxr);
  float acc = 0.f;
  int k4 = K >> 2;
  for (int k = 0; k < k4; ++k) {
    float4 a = x4[k], b = w4[k];
    acc += a.x * b.x + a.y * b.y + a.z * b.z + a.w * b.w;
  }
  y[(size_t)r * M + ob] = acc;
}

// ---------------- fused attention dots + logits + segment softmax ----------
template<int OC>
__global__ __launch_bounds__(256) void k_gnn_attsm(
    const float* __restrict__ y, const float* __restrict__ att,
    float* __restrict__ attw) {
  int t = threadIdx.x;
  __shared__ float sx_s[144], seb_s[60];
  __shared__ float a_s[536];
  if (t < 200) {
    int r = t >> 2, h = t & 3;
    const float4* row = reinterpret_cast<const float4*>(y + ((size_t)r * 4 + h) * OC);
    const float4* ar = reinterpret_cast<const float4*>(att + (size_t)h * 2 * OC + (r < 36 ? 0 : OC));
    float s = 0.f;
#pragma unroll 4
    for (int k = 0; k < OC / 4; ++k) {
      float4 a = row[k], b = ar[k];
      s += a.x * b.x + a.y * b.y + a.z * b.z + a.w * b.w;
    }
    if (r < 36) sx_s[r * 4 + h] = s; else seb_s[(r - 36) * 4 + h] = s;
  }
  __syncthreads();
  for (int idx = t; idx < 536; idx += 256) {
    int i = idx >> 2, h = idx & 3;
    float v = sx_s[c_row[i] * 4 + h] + seb_s[c_col[i] * 4 + h];
    a_s[idx] = (v > 0.f) ? v : 0.2f * v;
  }
  __syncthreads();
  if (t < 56) {
    int c = t >> 2, h = t & 3;
    int st = c_cs[c], en = c_cs[c + 1];
    float m = -1e30f;
    for (int i = st; i < en; ++i) m = fmaxf(m, a_s[i * 4 + h]);
    float s = 0.f;
    for (int i = st; i < en; ++i) { float e = __expf(a_s[i * 4 + h] - m); a_s[i * 4 + h] = e; s += e; }
    float inv = 1.f / (s + 1e-16f);
    for (int i = st; i < en; ++i) a_s[i * 4 + h] *= inv;
  }
  __syncthreads();
  for (int idx = t; idx < 536; idx += 256) attw[idx] = a_s[idx];
}

// ---------------- edge aggregation ----------------
template<int OC>
__global__ __launch_bounds__(256) void k_edge_agg(
    const float* __restrict__ y, const float* __restrict__ attw,
    float* __restrict__ eb) {
  int idx = blockIdx.x * 256 + threadIdx.x;
  if (idx >= 14 * 4 * OC) return;
  int ch = idx % OC;
  int h = (idx / OC) & 3;
  int c = idx / (4 * OC);
  int st = c_cs[c], en = c_cs[c + 1];
  float s = 0.f;
  for (int i = st; i < en; ++i)
    s += attw[i * 4 + h] * y[(size_t)c_row[i] * (4 * OC) + h * OC + ch];
  eb[idx] = s * (1.f / (float)(en - st));
}

// ---------------- node aggregation ----------------
template<int OC>
__global__ __launch_bounds__(256) void k_node_agg(
    const float* __restrict__ attw, const float* __restrict__ eb,
    const float* __restrict__ ew, float* __restrict__ ho) {
  int idx = blockIdx.x * 256 + threadIdx.x;
  if (idx >= 36 * OC) return;
  int ch = idx % OC;
  int node = idx / OC;
  int b = node / 18, ln = node % 18;
  int ncols, cols[4], gis[4];
  if (ln < 16) {
    ncols = 4;
    cols[0] = b * 7 + (ln < 8 ? 0 : 1); gis[0] = b * 67 + ln;
    cols[1] = b * 7 + 2; gis[1] = b * 67 + 16 + ln;
    cols[2] = b * 7 + 3; gis[2] = b * 67 + 32 + ln;
    cols[3] = b * 7 + 4; gis[3] = b * 67 + 48 + ln;
  } else if (ln == 16) {
    ncols = 2;
    cols[0] = b * 7 + 4; gis[0] = b * 67 + 64;
    cols[1] = b * 7 + 5; gis[1] = b * 67 + 65;
    cols[2] = cols[3] = 0; gis[2] = gis[3] = 0;
  } else {
    ncols = 1;
    cols[0] = b * 7 + 6; gis[0] = b * 67 + 66;
    cols[1] = cols[2] = cols[3] = 0; gis[1] = gis[2] = gis[3] = 0;
  }
  float dsum = 0.f;
#pragma unroll
  for (int k = 0; k < 4; ++k) if (k < ncols) dsum += ew[cols[k]];
  float D = dsum > 0.f ? 1.f / dsum : 0.f;
  float s = 0.f;
#pragma unroll
  for (int k = 0; k < 4; ++k) {
    if (k < ncols) {
#pragma unroll
      for (int h = 0; h < 4; ++h)
        s += attw[gis[k] * 4 + h] * eb[((size_t)cols[k] * 4 + h) * OC + ch];
    }
  }
  ho[idx] = fmaxf(0.25f * D * s, 0.f);
}

// ---------------- GroupNorm(32) + SE layer (+ optional fused observers) ----------
template<int C, int Cr, bool OBS>
__global__ __launch_bounds__(512) void k_gn_se(
    const float* __restrict__ hin, const float* __restrict__ w1,
    const float* __restrict__ w2, float* __restrict__ x,
    const float* __restrict__ tn, float* __restrict__ obsout) {
  int t = threadIdx.x;
  constexpr int gs = C >> 5;
  for (int idx = t; idx < 36 * 32; idx += 512) {
    int node = idx >> 5, g = idx & 31;
    const float* p = hin + (size_t)node * C + g * gs;
    float s = 0.f, s2 = 0.f;
#pragma unroll
    for (int k = 0; k < gs; ++k) { float v = p[k]; s += v; s2 += v * v; }
    float mu = s * (1.f / gs);
    float var = s2 * (1.f / gs) - mu * mu;
    float inv = rsqrtf(fmaxf(var, 0.f) + 1e-5f);
    float* q = x + (size_t)node * C + g * gs;
#pragma unroll
    for (int k = 0; k < gs; ++k) q[k] = (p[k] - mu) * inv;
  }
  __threadfence_block();
  __syncthreads();
  __shared__ float smean[C];
  __shared__ float spart[Cr][17];
  __shared__ float shid[Cr];
  __shared__ float sscale[C];
  if (t < C) {
    float s = 0.f;
    for (int nn = 0; nn < 36; ++nn) s += x[(size_t)nn * C + t];
    smean[t] = s * (1.f / 36.f);
  }
  __syncthreads();
  if (t < Cr * 16) {
    int hid = t >> 4, sub = t & 15;
    constexpr int CH = C / 16;
    float s = 0.f;
#pragma unroll
    for (int k = 0; k < CH; ++k)
      s += w1[(size_t)hid * C + sub * CH + k] * smean[sub * CH + k];
    spart[hid][sub] = s;
  }
  __syncthreads();
  if (t < Cr) {
    float s = 0.f;
#pragma unroll
    for (int k = 0; k < 16; ++k) s += spart[t][k];
    shid[t] = fmaxf(s, 0.f);
  }
  __syncthreads();
  if (t < C) {
    float s = 0.f;
#pragma unroll
    for (int k = 0; k < Cr; ++k) s += w2[(size_t)t * Cr + k] * shid[k];
    sscale[t] = 1.f / (1.f + __expf(-s));
  }
  __syncthreads();
  for (int idx = t; idx < 36 * C; idx += 512) x[idx] *= sscale[idx % C];
  if constexpr (OBS) {
    __threadfence();
    __syncthreads();
    if (t < 128) {
      int b = t >> 6, ch = t & 63;
      const float* a = tn + (size_t)b * 256 + ch * 4;
      const float* c = x + ((size_t)(b * 18 + 17)) * C + ch * 4;
      float m = a[0] + c[0];
      m = fmaxf(m, a[1] + c[1]);
      m = fmaxf(m, a[2] + c[2]);
      m = fmaxf(m, a[3] + c[3]);
      obsout[b * 64 + ch] = m;
    }
  }
}

extern "C" void kernel_launch(void* const* d_in, const int* in_sizes, int n_in,
                              void* d_out, int out_size, void* d_ws, size_t ws_size,
                              hipStream_t stream) {
  (void)in_sizes; (void)n_in; (void)out_size; (void)ws_size;
  const float* vf    = (const float*)d_in[0];
  const float* vp    = (const float*)d_in[1];
  const float* mf    = (const float*)d_in[2];
  const float* mp    = (const float*)d_in[3];
  const float* tf    = (const float*)d_in[4];
  const float* tp    = (const float*)d_in[5];
  const float* cv1w  = (const float*)d_in[6];
  const float* cv1b  = (const float*)d_in[7];
  const float* cv2w  = (const float*)d_in[8];
  const float* cv2b  = (const float*)d_in[9];
  const float* dc1w  = (const float*)d_in[10];
  const float* dc1b  = (const float*)d_in[11];
  const float* dc2w  = (const float*)d_in[12];
  const float* dc2b  = (const float*)d_in[13];
  const float* tc1w  = (const float*)d_in[14];
  const float* tc1b  = (const float*)d_in[15];
  const float* tc2w  = (const float*)d_in[16];
  const float* tc2b  = (const float*)d_in[17];
  const float* lin1w = (const float*)d_in[18];
  const float* att1  = (const float*)d_in[19];
  const float* lin2w = (const float*)d_in[20];
  const float* att2  = (const float*)d_in[21];
  const float* ew1   = (const float*)d_in[22];
  const float* ew2   = (const float*)d_in[23];
  const float* ea1   = (const float*)d_in[24];
  const float* ea2   = (const float*)d_in[25];
  const float* se1w1 = (const float*)d_in[26];
  const float* se1w2 = (const float*)d_in[27];
  const float* se2w1 = (const float*)d_in[28];
  const float* se2w2 = (const float*)d_in[29];

  float* ws  = (float*)d_ws;
  float* out = (float*)d_out;

  // workspace layout (float units); ~103 MB
  unsigned short* p0nm = (unsigned short*)(ws);             // motion input NHWC (later t1n)
  unsigned short* p0nv = (unsigned short*)(ws + 8388608);   // vision input NHWC (deconv2 residual)
  unsigned short* q1nb = (unsigned short*)(ws + 16777216);  // 32x64x64x128 bf16
  unsigned short* wtb  = (unsigned short*)(ws + 25165824);  // 1,105,920 bf16
  float* sm   = ws + 25718784;
  float* tn   = sm;                 // 512
  float* nb   = sm + 512;           // 8192
  float* x0   = sm + 8704;          // 9216
  float* xl   = sm + 17920;         // 102400
  float* eb   = sm + 120520;        // 28672
  float* ho   = sm + 149192;        // 18432
  float* x1   = sm + 167624;        // 18432
  float* x2   = sm + 186056;        // 9216
  float* attw = sm + 195272;        // 536
  float* pmax = sm + 195904;        // 65536

  unsigned short* v2nb = (unsigned short*)d_out;  // dead region before deconv2 rewrites it
  unsigned short* t1n = (unsigned short*)(ws);

  unsigned short* wTc1 = wtb;
  unsigned short* wTd1 = wtb + 73728;
  unsigned short* wTc2 = wtb + 147456;
  unsigned short* wTd2 = wtb + 442368;
  unsigned short* wTt1 = wtb + 737280;
  unsigned short* wTt2 = wtb + 1032192;

  // 0. fused: input prep (both branches, 1KB-chunk reads) + weight transforms
  k_prep_all<<<4208, 512, 0, stream>>>(mf, mp, vf, vp, p0nm, p0nv,
                                       cv1w, dc1w, cv2w, dc2w, tc1w, tc2w, wtb);

  // 1. encoder, batched (n 0-15 motion, 16-31 vision)
  k_conv_mfma_b<64, 128, 64, 64, 1, true><<<2048, 512, 0, stream>>>(
      p0nm, p0nv, wTd1, wTc1, dc1b, cv1b, q1nb);
  k_conv_mfma_b<128, 256, 32, 32, 2, false><<<1024, 512, 0, stream>>>(
      q1nb, nullptr, wTd2, wTc2, dc2b, cv2b, v2nb);
  k_max_part<<<256, 256, 0, stream>>>(v2nb, pmax);
  k_ln<<<32, 256, 0, stream>>>(pmax, nb);

  // 2. node features
  k_build_x<<<2, 256, 0, stream>>>(tf, tp, nb, tn, x0);

  // 3. GNN layer 1 (OC=512)
  k_gnn_lin<<<50 * 8, 256, 0, stream>>>(x0, ea1, lin1w, xl, 256, 2048);
  k_gnn_attsm<512><<<1, 256, 0, stream>>>(xl, att1, attw);
  k_edge_agg<512><<<112, 256, 0, stream>>>(xl, attw, eb);
  k_node_agg<512><<<72, 256, 0, stream>>>(attw, eb, ew1, ho);
  k_gn_se<512, 32, false><<<1, 512, 0, stream>>>(ho, se1w1, se1w2, x1, nullptr, nullptr);

  // 4. GNN layer 2 (OC=256), observers fused into gn_se
  k_gnn_lin<<<50 * 4, 256, 0, stream>>>(x1, ea2, lin2w, xl, 512, 1024);
  k_gnn_attsm<256><<<1, 256, 0, stream>>>(xl, att2, attw);
  k_edge_agg<256><<<56, 256, 0, stream>>>(xl, attw, eb);
  k_node_agg<256><<<36, 256, 0, stream>>>(attw, eb, ew2, ho);
  k_gn_se<256, 16, true><<<1, 512, 0, stream>>>(ho, se2w1, se2w2, x2, tn, out + 16777216);

  // 5. decoder (vision halves)
  unsigned short* v2nv = v2nb + 4194304;
  unsigned short* q1nv = q1nb + 8388608;
  k_deconv_mfma<256, 128, 32, 32, 2, true, true><<<512, 256, 0, stream>>>(
      v2nv, wTt1, tc1b, q1nv, x2, t1n, nullptr);
  k_deconv_mfma<128, 64, 64, 64, 1, false, false><<<1024, 256, 0, stream>>>(
      t1n, wTt2, tc2b, p0nv, nullptr, nullptr, out);
}

// Round 22
// 453.012 us; speedup vs baseline: 1.0057x; 1.0057x over previous
//
#include <hip/hip_runtime.h>
#include <hip/hip_bf16.h>
#include <cstddef>
#include <cstdint>

#define DEV_INLINE __device__ __forceinline__
#define AS1 __attribute__((address_space(1)))
#define AS3 __attribute__((address_space(3)))

typedef __attribute__((ext_vector_type(8))) short short8;
typedef __attribute__((ext_vector_type(4))) float f32x4;
typedef __attribute__((ext_vector_type(2))) float f32x2;
typedef __attribute__((ext_vector_type(4))) unsigned short us4;

DEV_INLINE unsigned short f2bf(float f) {
  uint32_t u = __builtin_bit_cast(uint32_t, f);
  uint32_t r = (u + 0x7fffu + ((u >> 16) & 1u)) >> 16;
  return (unsigned short)r;
}
DEV_INLINE float bf2f(unsigned short u) {
  return __builtin_bit_cast(float, (uint32_t)u << 16);
}

DEV_INLINE void gl_lds16(const float* g, float* l) {
  __builtin_amdgcn_global_load_lds((AS1 void*)const_cast<float*>(g),
                                   (AS3 void*)l, 16, 0, 0);
}

// Problem constants: BS=2, F=8, C=64, H=128, W=128, HEADS=4
__device__ __constant__ int c_cs[15] = {0,8,16,32,48,65,66,67,75,83,99,115,132,133,134};
__device__ __constant__ int c_row[134] = {
  0,1,2,3,4,5,6,7,
  8,9,10,11,12,13,14,15,
  0,1,2,3,4,5,6,7,8,9,10,11,12,13,14,15,
  0,1,2,3,4,5,6,7,8,9,10,11,12,13,14,15,
  0,1,2,3,4,5,6,7,8,9,10,11,12,13,14,15,16,
  16,
  17,
  18,19,20,21,22,23,24,25,
  26,27,28,29,30,31,32,33,
  18,19,20,21,22,23,24,25,26,27,28,29,30,31,32,33,
  18,19,20,21,22,23,24,25,26,27,28,29,30,31,32,33,
  18,19,20,21,22,23,24,25,26,27,28,29,30,31,32,33,34,
  34,
  35
};
__device__ __constant__ int c_col[134] = {
  0,0,0,0,0,0,0,0,
  1,1,1,1,1,1,1,1,
  2,2,2,2,2,2,2,2,2,2,2,2,2,2,2,2,
  3,3,3,3,3,3,3,3,3,3,3,3,3,3,3,3,
  4,4,4,4,4,4,4,4,4,4,4,4,4,4,4,4,4,
  5,
  6,
  7,7,7,7,7,7,7,7,
  8,8,8,8,8,8,8,8,
  9,9,9,9,9,9,9,9,9,9,9,9,9,9,9,9,
  10,10,10,10,10,10,10,10,10,10,10,10,10,10,10,10,
  11,11,11,11,11,11,11,11,11,11,11,11,11,11,11,11,11,
  12,
  13
};

// LDS chunk offset for prep: 16B-aligned, bank-spreading
DEV_INLINE int pofs(int ci) { return 260 * ci + 4 * (ci >> 3); }

// ---------------- fused: batched input prep + weight transforms + pmax zero ----------
__global__ __launch_bounds__(512) void k_prep_all(
    const float* __restrict__ mf, const float* __restrict__ mp,
    const float* __restrict__ vf, const float* __restrict__ vp,
    unsigned short* __restrict__ p0nm, unsigned short* __restrict__ p0nv,
    const float* __restrict__ cv1w, const float* __restrict__ dc1w,
    const float* __restrict__ cv2w, const float* __restrict__ dc2w,
    const float* __restrict__ tc1w, const float* __restrict__ tc2w,
    unsigned short* __restrict__ wtb, float* __restrict__ pmaxp) {
  __shared__ float sbuf[16664];
  int bid = blockIdx.x;
  int t = threadIdx.x;
  if (bid >= 2048) {
    int idx = (bid - 2048) * 512 + t;
    if (idx < 8192) pmaxp[idx] = 0.f;   // zero pmax for fused conv2 max (values >= 0)
    if (idx >= 1105920) return;
    const float* src; int off, lci, lco; bool tra;
    if (idx < 73728)        { src = cv1w; off = 0;       lci = 6; lco = 7; tra = false; }
    else if (idx < 147456)  { src = dc1w; off = 73728;   lci = 6; lco = 7; tra = false; }
    else if (idx < 442368)  { src = cv2w; off = 147456;  lci = 7; lco = 8; tra = false; }
    else if (idx < 737280)  { src = dc2w; off = 442368;  lci = 7; lco = 8; tra = false; }
    else if (idx < 1032192) { src = tc1w; off = 737280;  lci = 8; lco = 7; tra = true;  }
    else                    { src = tc2w; off = 1032192; lci = 7; lco = 6; tra = true;  }
    int l = idx - off;
    int ci = l & ((1 << lci) - 1);
    int r = l >> lci;
    int co = r & ((1 << lco) - 1);
    int tap = r >> lco;
    size_t si = tra ? (((size_t)ci << lco) + co) * 9 + tap
                    : (((size_t)co << lci) + ci) * 9 + tap;
    wtb[idx] = f2bf(src[si]);
    return;
  }
  const float* a = (bid < 1024) ? mf : vf;
  const float* b = (bid < 1024) ? mp : vp;
  unsigned short* o = (bid < 1024) ? p0nm : p0nv;
  int b2 = bid & 1023;
  int yb = b2 & 63, n = b2 >> 6;
  int y0 = yb * 2;
  int w = t >> 6, lane = t & 63;
  const size_t srcbase = ((size_t)n * 64) * 16384 + (size_t)y0 * 128 + lane * 4;
#pragma unroll
  for (int k = 0; k < 8; ++k) {
    int ci = w * 8 + k;
    gl_lds16(a + srcbase + (size_t)ci * 16384, &sbuf[pofs(ci)]);
  }
  __syncthreads();
  auto rd = [&](int ci, int yy, int x) {
    return sbuf[pofs(ci) + yy * 128 + x];
  };
  float av[2][2][8];
#pragma unroll
  for (int it = 0; it < 2; ++it) {
    int i = t + it * 512;
    int x = i >> 3, cq = i & 7;
#pragma unroll
    for (int yy = 0; yy < 2; ++yy)
#pragma unroll
      for (int j = 0; j < 8; ++j) av[it][yy][j] = rd(cq * 8 + j, yy, x);
  }
  __syncthreads();
#pragma unroll
  for (int k = 0; k < 8; ++k) {
    int ci = w * 8 + k;
    gl_lds16(b + srcbase + (size_t)ci * 16384, &sbuf[pofs(ci)]);
  }
  __syncthreads();
#pragma unroll
  for (int it = 0; it < 2; ++it) {
    int i = t + it * 512;
    int x = i >> 3, cq = i & 7;
#pragma unroll
    for (int yy = 0; yy < 2; ++yy) {
      unsigned int* op = (unsigned int*)(o + (((size_t)n * 128 + y0 + yy) * 128) * 64);
      uint4 v;
      unsigned int vv[4];
#pragma unroll
      for (int jj = 0; jj < 4; ++jj) {
        unsigned int lo = f2bf(av[it][yy][2 * jj]     + rd(cq * 8 + 2 * jj, yy, x));
        unsigned int hi = f2bf(av[it][yy][2 * jj + 1] + rd(cq * 8 + 2 * jj + 1, yy, x));
        vv[jj] = lo | (hi << 16);
      }
      v.x = vv[0]; v.y = vv[1]; v.z = vv[2]; v.w = vv[3];
      *reinterpret_cast<uint4*>(op + x * 32 + cq * 4) = v;
    }
  }
}

// ---------------- Conv2d k3 s2 p1 + bias + ReLU via bf16 MFMA (branch-batched) -------
// PMAX: fuse per-(n,co) spatial max into epilogue via LDS+global atomicMax (vals >= 0).
template<int CI, int CO, int HO, int WO, int ROUT, bool SPLIT_IN, bool PMAX>
__global__ __launch_bounds__(512, 3) void k_conv_mfma_b(
    const unsigned short* __restrict__ in0, const unsigned short* __restrict__ in1,
    const unsigned short* __restrict__ wT0, const unsigned short* __restrict__ wT1,
    const float* __restrict__ b0, const float* __restrict__ b1,
    unsigned short* __restrict__ outn, float* __restrict__ pmaxp) {
  constexpr int HIN = HO * 2, WIN = WO * 2;
  constexpr int XHP = WO + 2;
  constexpr int R = 2 * ROUT + 1;
  constexpr int NPOS = R * 2 * XHP;
  constexpr int NCH = NPOS * 4;
  constexpr int NCS = CI / 32;
  constexpr int KIT = (NCH + 511) / 512;
  constexpr int CB = CO / 128;
  constexpr int OB = HO / ROUT;
  __shared__ short8 sIn[NPOS * 5];
  __shared__ unsigned smax[128];
  int bid = blockIdx.x;
  int cb = bid % CB; bid /= CB;
  int oyb = bid % OB; int n = bid / OB;     // n 0..31
  int br = n >> 4;
  const unsigned short* in = SPLIT_IN ? (br ? in1 : in0) : in0;
  const unsigned short* wT = br ? wT1 : wT0;
  const float* bias = br ? b1 : b0;
  int ni = SPLIT_IN ? (n & 15) : n;
  int tid = threadIdx.x;
  int wid = tid >> 6, lane = tid & 63;
  int wm = wid >> 1, wn = wid & 1;
  int llo = lane & 15, lhi = lane >> 4;
  f32x4 acc[2][2] = {};
  const int iy0 = oyb * (2 * ROUT) - 1;
  if constexpr (PMAX) {
    if (tid < 128) smax[tid] = 0u;
  }
  short8 rv[KIT];
  auto loadr = [&](int cs) {
#pragma unroll
    for (int k = 0; k < KIT; ++k) {
      int i = tid + k * 512;
      short8 v = {};
      if (i < NCH) {
        int c = i & 3, q = i >> 2;
        int xh = q % XHP; int q2 = q / XHP;
        int p = q2 & 1, l = q2 >> 1;
        int x = 2 * xh + p - 1;
        int iy = iy0 + l;
        if (x >= 0 && x < WIN && iy >= 0 && iy < HIN)
          v = *reinterpret_cast<const short8*>(in + ((((size_t)ni * HIN + iy) * WIN + x) * CI + cs * 32 + c * 8));
      }
      rv[k] = v;
    }
  };
  auto writes = [&]() {
#pragma unroll
    for (int k = 0; k < KIT; ++k) {
      int i = tid + k * 512;
      if (i < NCH) sIn[(i >> 2) * 5 + (i & 3)] = rv[k];
    }
  };
  loadr(0);
  for (int cs = 0; cs < NCS; ++cs) {
    writes();
    __syncthreads();
    if (cs + 1 < NCS) loadr(cs + 1);
    short8 afr9[9][2];
#pragma unroll
    for (int tap = 0; tap < 9; ++tap)
#pragma unroll
      for (int m = 0; m < 2; ++m) {
        int co = cb * 128 + wm * 32 + m * 16 + llo;
        afr9[tap][m] = *reinterpret_cast<const short8*>(wT + (((size_t)tap * CO + co) * CI + cs * 32 + lhi * 8));
      }
#pragma unroll
    for (int tap = 0; tap < 9; ++tap) {
      const int ky = tap / 3, kx = tap % 3;
      short8 bfr[2];
#pragma unroll
      for (int n2 = 0; n2 < 2; ++n2) {
        int pix = wn * 32 + n2 * 16 + llo;
        int oyl = (ROUT == 2) ? (pix >> 5) : 0;
        int ox = pix - oyl * WO;
        int lrow = 2 * oyl + ky;
        int pos = (lrow * 2 + (kx & 1)) * XHP + ox + (kx >> 1);
        bfr[n2] = sIn[pos * 5 + lhi];
      }
#pragma unroll
      for (int m = 0; m < 2; ++m)
#pragma unroll
        for (int n2 = 0; n2 < 2; ++n2)
          acc[m][n2] = __builtin_amdgcn_mfma_f32_16x16x32_bf16(afr9[tap][m], bfr[n2], acc[m][n2], 0, 0, 0);
    }
    __syncthreads();
  }
#pragma unroll
  for (int m = 0; m < 2; ++m) {
    int co0 = cb * 128 + wm * 32 + m * 16 + lhi * 4;
    f32x4 bv = *reinterpret_cast<const f32x4*>(bias + co0);
    float tmax[4] = {0.f, 0.f, 0.f, 0.f};
#pragma unroll
    for (int n2 = 0; n2 < 2; ++n2) {
      int pix = wn * 32 + n2 * 16 + llo;
      int oyl = (ROUT == 2) ? (pix >> 5) : 0;
      int ox = pix - oyl * WO;
      int oy = oyb * ROUT + oyl;
      float v0 = fmaxf(acc[m][n2][0] + bv[0], 0.f);
      float v1 = fmaxf(acc[m][n2][1] + bv[1], 0.f);
      float v2 = fmaxf(acc[m][n2][2] + bv[2], 0.f);
      float v3 = fmaxf(acc[m][n2][3] + bv[3], 0.f);
      if constexpr (PMAX) {
        tmax[0] = fmaxf(tmax[0], v0); tmax[1] = fmaxf(tmax[1], v1);
        tmax[2] = fmaxf(tmax[2], v2); tmax[3] = fmaxf(tmax[3], v3);
      }
      us4 pk;
      pk[0] = f2bf(v0); pk[1] = f2bf(v1); pk[2] = f2bf(v2); pk[3] = f2bf(v3);
      *reinterpret_cast<us4*>(outn + ((((size_t)n * HO + oy) * WO + ox) * CO + co0)) = pk;
    }
    if constexpr (PMAX) {
      int lbase = wm * 32 + m * 16 + lhi * 4;
#pragma unroll
      for (int c = 0; c < 4; ++c)
        atomicMax(&smax[lbase + c], __float_as_uint(tmax[c]));
    }
  }
  if constexpr (PMAX) {
    __syncthreads();
    if (tid < 128)
      atomicMax((unsigned int*)(pmaxp + (size_t)n * 256 + cb * 128 + tid), smax[tid]);
  }
}

// ---------------- ConvTranspose2d k3 s2 p1 op1 via bf16 MFMA (round-14 shape) --------
template<int CI, int CO, int Hi, int Wi, int QR, bool OBF, bool GADD>
__global__ __launch_bounds__(256, 3) void k_deconv_mfma(
    const unsigned short* __restrict__ in,
    const unsigned short* __restrict__ wT,
    const float* __restrict__ bias,
    const unsigned short* __restrict__ resn,
    const float* __restrict__ gsrc,
    unsigned short* __restrict__ outn,
    float* __restrict__ outc) {
  constexpr int QC = 64 / QR;
  constexpr int WP = Wi + 1;
  constexpr int NPOS = (QR + 1) * WP;
  constexpr int NCH = NPOS * 4;
  constexpr int NCS = CI / 32;
  constexpr int KIT = (NCH + 255) / 256;
  constexpr int CB = CO / 64;
  constexpr int OB = Hi / QR;
  constexpr int Ho = Hi * 2, Wo = Wi * 2;
  __shared__ short8 sIn[NPOS * 5];
  int bid = blockIdx.x;
  int cb = bid % CB; bid /= CB;
  int oyb = bid % OB; int n = bid / OB;
  int tid = threadIdx.x;
  int wid = tid >> 6, lane = tid & 63;
  int wm = wid >> 1, wn = wid & 1;
  int llo = lane & 15, lhi = lane >> 4;
  int qy0 = oyb * QR;
  const float* g = nullptr;
  if constexpr (GADD) g = gsrc + ((size_t)((n >> 3) * 18 + (n & 7))) * 256;
  f32x4 acc[4][2][2] = {};
  constexpr int tap_p[9] = {3,2,3,1,0,1,3,2,3};
  constexpr int tap_b[9] = {3,2,2,1,0,0,1,0,0};
  short8 rv[KIT];
  auto loadr = [&](int cs) {
#pragma unroll
    for (int k = 0; k < KIT; ++k) {
      int i = tid + k * 256;
      short8 v = {};
      if (i < NCH) {
        int c = i & 3, q = i >> 2;
        int x = q % WP, l = q / WP;
        int iy = qy0 + l;
        if (x < Wi && iy < Hi) {
          v = *reinterpret_cast<const short8*>(in + (((size_t)(n * Hi + iy) * Wi + x) * CI + cs * 32 + c * 8));
          if constexpr (GADD) {
#pragma unroll
            for (int j = 0; j < 8; ++j) {
              float fv = bf2f((unsigned short)v[j]) + g[cs * 32 + c * 8 + j];
              v[j] = (short)f2bf(fv);
            }
          }
        }
      }
      rv[k] = v;
    }
  };
  auto writes = [&]() {
#pragma unroll
    for (int k = 0; k < KIT; ++k) {
      int i = tid + k * 256;
      if (i < NCH) sIn[(i >> 2) * 5 + (i & 3)] = rv[k];
    }
  };
  loadr(0);
  for (int cs = 0; cs < NCS; ++cs) {
    writes();
    __syncthreads();
    if (cs + 1 < NCS) loadr(cs + 1);
    short8 bfr[2][4];
#pragma unroll
    for (int n2 = 0; n2 < 2; ++n2) {
      int pix = wn * 32 + n2 * 16 + llo;
      int qyl = pix / QC, qx = pix % QC;
#pragma unroll
      for (int bs = 0; bs < 4; ++bs) {
        int pos = (qyl + (bs >> 1)) * WP + qx + (bs & 1);
        bfr[n2][bs] = sIn[pos * 5 + lhi];
      }
    }
#pragma unroll
    for (int m = 0; m < 2; ++m) {
      short8 afr9[9];
#pragma unroll
      for (int tap = 0; tap < 9; ++tap) {
        int co = cb * 64 + wm * 32 + m * 16 + llo;
        afr9[tap] = *reinterpret_cast<const short8*>(wT + (((size_t)tap * CO + co) * CI + cs * 32 + lhi * 8));
      }
#pragma unroll
      for (int tap = 0; tap < 9; ++tap)
#pragma unroll
        for (int n2 = 0; n2 < 2; ++n2)
          acc[tap_p[tap]][m][n2] = __builtin_amdgcn_mfma_f32_16x16x32_bf16(
              afr9[tap], bfr[n2][tap_b[tap]], acc[tap_p[tap]][m][n2], 0, 0, 0);
    }
    __syncthreads();
  }
#pragma unroll
  for (int m = 0; m < 2; ++m) {
    int co0 = cb * 64 + wm * 32 + m * 16 + lhi * 4;
    f32x4 bv = *reinterpret_cast<const f32x4*>(bias + co0);
#pragma unroll
    for (int n2 = 0; n2 < 2; ++n2) {
      int pix = wn * 32 + n2 * 16 + llo;
      int qyl = pix / QC, qx = pix % QC;
      int qy = qy0 + qyl;
      if constexpr (OBF) {
#pragma unroll
        for (int p = 0; p < 4; ++p) {
          int oy = 2 * qy + (p >> 1);
          int ox = 2 * qx + (p & 1);
          size_t ad = ((size_t)(n * Ho + oy) * Wo + ox) * CO + co0;
          us4 r = *reinterpret_cast<const us4*>(resn + ad);
          us4 pk;
#pragma unroll
          for (int c = 0; c < 4; ++c)
            pk[c] = f2bf(bf2f(r[c]) + fmaxf(acc[p][m][n2][c] + bv[c], 0.f));
          *reinterpret_cast<us4*>(outn + ad) = pk;
        }
      } else {
        int qx2 = 2 * qx;
#pragma unroll
        for (int dy = 0; dy < 2; ++dy) {
          int oy = 2 * qy + dy;
          size_t rb = ((size_t)(n * Ho + oy) * Wo + qx2) * CO + co0;
          us4 r0 = *reinterpret_cast<const us4*>(resn + rb);
          us4 r1 = *reinterpret_cast<const us4*>(resn + rb + CO);
#pragma unroll
          for (int c = 0; c < 4; ++c) {
            f32x2 st;
            st[0] = bf2f(r0[c]) + fmaxf(acc[dy * 2][m][n2][c] + bv[c], 0.f);
            st[1] = bf2f(r1[c]) + fmaxf(acc[dy * 2 + 1][m][n2][c] + bv[c], 0.f);
            __builtin_nontemporal_store(st,
                reinterpret_cast<f32x2*>(outc + ((size_t)(n * CO + co0 + c) * Ho + oy) * Wo + qx2));
          }
        }
      }
    }
  }
}

// ---------------- LayerNorm over 256 channels (reads fused pmax directly) ----------
__global__ __launch_bounds__(256) void k_ln(const float* __restrict__ pmax,
                                            float* __restrict__ out) {
  int n = blockIdx.x, ch = threadIdx.x;
  float m = pmax[(size_t)n * 256 + ch];
  __shared__ float r1[256], r2[256];
  r1[ch] = m; __syncthreads();
  for (int s = 128; s > 0; s >>= 1) { if (ch < s) r1[ch] += r1[ch + s]; __syncthreads(); }
  float mu = r1[0] * (1.f / 256.f);
  float d = m - mu;
  r2[ch] = d * d; __syncthreads();
  for (int s = 128; s > 0; s >>= 1) { if (ch < s) r2[ch] += r2[ch + s]; __syncthreads(); }
  out[(size_t)n * 256 + ch] = d * rsqrtf(r2[0] * (1.f / 256.f) + 1e-5f);
}

// ---------------- build node features (text pool fused in) ----------------
__global__ void k_build_x(const float* __restrict__ tf, const float* __restrict__ tp,
                          const float* __restrict__ nb,
                          float* __restrict__ tn, float* __restrict__ x0) {
  int b = blockIdx.x, ch = threadIdx.x;
  int c4 = ch >> 2, j = ch & 3;
  const float* p = tf + ((size_t)b * 64 + c4) * 16 + j * 4;
  const float* q = tp + ((size_t)b * 64 + c4) * 16 + j * 4;
  float tv = p[0] + q[0];
  tv = fmaxf(tv, p[1] + q[1]);
  tv = fmaxf(tv, p[2] + q[2]);
  tv = fmaxf(tv, p[3] + q[3]);
  tn[(size_t)b * 256 + ch] = tv;
  const float* dn = nb;
  const float* vn = nb + 16 * 256;
  float s = 0.f;
  for (int f = 0; f < 8; ++f) {
    float vv = vn[((size_t)b * 8 + f) * 256 + ch];
    float dd = dn[((size_t)b * 8 + f) * 256 + ch];
    s += vv + dd;
    x0[((size_t)b * 18 + f) * 256 + ch] = vv;
    x0[((size_t)b * 18 + 8 + f) * 256 + ch] = dd;
  }
  x0[((size_t)b * 18 + 16) * 256 + ch] = tv;
  x0[((size_t)b * 18 + 17) * 256 + ch] = tv + s * (1.f / 8.f);
}

// ---------------- GNN linear ----------------
__global__ __launch_bounds__(256) void k_gnn_lin(
    const float* __restrict__ x, const float* __restrict__ ea,
    const float* __restrict__ w, float* __restrict__ y, int K, int M) {
  int chunks = M >> 8;
  int r = blockIdx.x / chunks;
  int ob = (blockIdx.x % chunks) * 256 + threadIdx.x;
  const float* src = (r < 36) ? (x + (size_t)r * K) : (ea + (size_t)(r - 36) * K);
  __shared__ __align__(16) float sxr[512];
  for (int k = threadIdx.x; k < K; k += 256) sxr[k] = src[k];
  __syncthreads();
  const float4* w4 = reinterpret_cast<const float4*>(w + (size_t)ob * K);
  const float4* x4 = reinterpret_cast<const float4*>(sxr);
  float acc = 0.f;
  int k4 = K >> 2;
  for (int k = 0; k < k4; ++k) {
    float4 a = x4[k], b = w4[k];
    acc += a.x * b.x + a.y * b.y + a.z * b.z + a.w * b.w;
  }
  y[(size_t)r * M + ob] = acc;
}

// ---------------- fused attention dots + logits + segment softmax ----------
template<int OC>
__global__ __launch_bounds__(256) void k_gnn_attsm(
    const float* __restrict__ y, const float* __restrict__ att,
    float* __restrict__ attw) {
  int t = threadIdx.x;
  __shared__ float sx_s[144], seb_s[60];
  __shared__ float a_s[536];
  if (t < 200) {
    int r = t >> 2, h = t & 3;
    const float4* row = reinterpret_cast<const float4*>(y + ((size_t)r * 4 + h) * OC);
    const float4* ar = reinterpret_cast<const float4*>(att + (size_t)h * 2 * OC + (r < 36 ? 0 : OC));
    float s = 0.f;
#pragma unroll 4
    for (int k = 0; k < OC / 4; ++k) {
      float4 a = row[k], b = ar[k];
      s += a.x * b.x + a.y * b.y + a.z * b.z + a.w * b.w;
    }
    if (r < 36) sx_s[r * 4 + h] = s; else seb_s[(r - 36) * 4 + h] = s;
  }
  __syncthreads();
  for (int idx = t; idx < 536; idx += 256) {
    int i = idx >> 2, h = idx & 3;
    float v = sx_s[c_row[i] * 4 + h] + seb_s[c_col[i] * 4 + h];
    a_s[idx] = (v > 0.f) ? v : 0.2f * v;
  }
  __syncthreads();
  if (t < 56) {
    int c = t >> 2, h = t & 3;
    int st = c_cs[c], en = c_cs[c + 1];
    float m = -1e30f;
    for (int i = st; i < en; ++i) m = fmaxf(m, a_s[i * 4 + h]);
    float s = 0.f;
    for (int i = st; i < en; ++i) { float e = __expf(a_s[i * 4 + h] - m); a_s[i * 4 + h] = e; s += e; }
    float inv = 1.f / (s + 1e-16f);
    for (int i = st; i < en; ++i) a_s[i * 4 + h] *= inv;
  }
  __syncthreads();
  for (int idx = t; idx < 536; idx += 256) attw[idx] = a_s[idx];
}

// ---------------- edge aggregation ----------------
template<int OC>
__global__ __launch_bounds__(256) void k_edge_agg(
    const float* __restrict__ y, const float* __restrict__ attw,
    float* __restrict__ eb) {
  int idx = blockIdx.x * 256 + threadIdx.x;
  if (idx >= 14 * 4 * OC) return;
  int ch = idx % OC;
  int h = (idx / OC) & 3;
  int c = idx / (4 * OC);
  int st = c_cs[c], en = c_cs[c + 1];
  float s = 0.f;
  for (int i = st; i < en; ++i)
    s += attw[i * 4 + h] * y[(size_t)c_row[i] * (4 * OC) + h * OC + ch];
  eb[idx] = s * (1.f / (float)(en - st));
}

// ---------------- node aggregation ----------------
template<int OC>
__global__ __launch_bounds__(256) void k_node_agg(
    const float* __restrict__ attw, const float* __restrict__ eb,
    const float* __restrict__ ew, float* __restrict__ ho) {
  int idx = blockIdx.x * 256 + threadIdx.x;
  if (idx >= 36 * OC) return;
  int ch = idx % OC;
  int node = idx / OC;
  int b = node / 18, ln = node % 18;
  int ncols, cols[4], gis[4];
  if (ln < 16) {
    ncols = 4;
    cols[0] = b * 7 + (ln < 8 ? 0 : 1); gis[0] = b * 67 + ln;
    cols[1] = b * 7 + 2; gis[1] = b * 67 + 16 + ln;
    cols[2] = b * 7 + 3; gis[2] = b * 67 + 32 + ln;
    cols[3] = b * 7 + 4; gis[3] = b * 67 + 48 + ln;
  } else if (ln == 16) {
    ncols = 2;
    cols[0] = b * 7 + 4; gis[0] = b * 67 + 64;
    cols[1] = b * 7 + 5; gis[1] = b * 67 + 65;
    cols[2] = cols[3] = 0; gis[2] = gis[3] = 0;
  } else {
    ncols = 1;
    cols[0] = b * 7 + 6; gis[0] = b * 67 + 66;
    cols[1] = cols[2] = cols[3] = 0; gis[1] = gis[2] = gis[3] = 0;
  }
  float dsum = 0.f;
#pragma unroll
  for (int k = 0; k < 4; ++k) if (k < ncols) dsum += ew[cols[k]];
  float D = dsum > 0.f ? 1.f / dsum : 0.f;
  float s = 0.f;
#pragma unroll
  for (int k = 0; k < 4; ++k) {
    if (k < ncols) {
#pragma unroll
      for (int h = 0; h < 4; ++h)
        s += attw[gis[k] * 4 + h] * eb[((size_t)cols[k] * 4 + h) * OC + ch];
    }
  }
  ho[idx] = fmaxf(0.25f * D * s, 0.f);
}

// ---------------- GroupNorm(32) + SE layer (+ optional fused observers) ----------
template<int C, int Cr, bool OBS>
__global__ __launch_bounds__(512) void k_gn_se(
    const float* __restrict__ hin, const float* __restrict__ w1,
    const float* __restrict__ w2, float* __restrict__ x,
    const float* __restrict__ tn, float* __restrict__ obsout) {
  int t = threadIdx.x;
  constexpr int gs = C >> 5;
  for (int idx = t; idx < 36 * 32; idx += 512) {
    int node = idx >> 5, g = idx & 31;
    const float* p = hin + (size_t)node * C + g * gs;
    float s = 0.f, s2 = 0.f;
#pragma unroll
    for (int k = 0; k < gs; ++k) { float v = p[k]; s += v; s2 += v * v; }
    float mu = s * (1.f / gs);
    float var = s2 * (1.f / gs) - mu * mu;
    float inv = rsqrtf(fmaxf(var, 0.f) + 1e-5f);
    float* q = x + (size_t)node * C + g * gs;
#pragma unroll
    for (int k = 0; k < gs; ++k) q[k] = (p[k] - mu) * inv;
  }
  __threadfence_block();
  __syncthreads();
  __shared__ float smean[C];
  __shared__ float spart[Cr][17];
  __shared__ float shid[Cr];
  __shared__ float sscale[C];
  if (t < C) {
    float s = 0.f;
    for (int nn = 0; nn < 36; ++nn) s += x[(size_t)nn * C + t];
    smean[t] = s * (1.f / 36.f);
  }
  __syncthreads();
  if (t < Cr * 16) {
    int hid = t >> 4, sub = t & 15;
    constexpr int CH = C / 16;
    float s = 0.f;
#pragma unroll
    for (int k = 0; k < CH; ++k)
      s += w1[(size_t)hid * C + sub * CH + k] * smean[sub * CH + k];
    spart[hid][sub] = s;
  }
  __syncthreads();
  if (t < Cr) {
    float s = 0.f;
#pragma unroll
    for (int k = 0; k < 16; ++k) s += spart[t][k];
    shid[t] = fmaxf(s, 0.f);
  }
  __syncthreads();
  if (t < C) {
    float s = 0.f;
#pragma unroll
    for (int k = 0; k < Cr; ++k) s += w2[(size_t)t * Cr + k] * shid[k];
    sscale[t] = 1.f / (1.f + __expf(-s));
  }
  __syncthreads();
  for (int idx = t; idx < 36 * C; idx += 512) x[idx] *= sscale[idx % C];
  if constexpr (OBS) {
    __threadfence();
    __syncthreads();
    if (t < 128) {
      int b = t >> 6, ch = t & 63;
      const float* a = tn + (size_t)b * 256 + ch * 4;
      const float* c = x + ((size_t)(b * 18 + 17)) * C + ch * 4;
      float m = a[0] + c[0];
      m = fmaxf(m, a[1] + c[1]);
      m = fmaxf(m, a[2] + c[2]);
      m = fmaxf(m, a[3] + c[3]);
      obsout[b * 64 + ch] = m;
    }
  }
}

extern "C" void kernel_launch(void* const* d_in, const int* in_sizes, int n_in,
                              void* d_out, int out_size, void* d_ws, size_t ws_size,
                              hipStream_t stream) {
  (void)in_sizes; (void)n_in; (void)out_size; (void)ws_size;
  const float* vf    = (const float*)d_in[0];
  const float* vp    = (const float*)d_in[1];
  const float* mf    = (const float*)d_in[2];
  const float* mp    = (const float*)d_in[3];
  const float* tf    = (const float*)d_in[4];
  const float* tp    = (const float*)d_in[5];
  const float* cv1w  = (const float*)d_in[6];
  const float* cv1b  = (const float*)d_in[7];
  const float* cv2w  = (const float*)d_in[8];
  const float* cv2b  = (const float*)d_in[9];
  const float* dc1w  = (const float*)d_in[10];
  const float* dc1b  = (const float*)d_in[11];
  const float* dc2w  = (const float*)d_in[12];
  const float* dc2b  = (const float*)d_in[13];
  const float* tc1w  = (const float*)d_in[14];
  const float* tc1b  = (const float*)d_in[15];
  const float* tc2w  = (const float*)d_in[16];
  const float* tc2b  = (const float*)d_in[17];
  const float* lin1w = (const float*)d_in[18];
  const float* att1  = (const float*)d_in[19];
  const float* lin2w = (const float*)d_in[20];
  const float* att2  = (const float*)d_in[21];
  const float* ew1   = (const float*)d_in[22];
  const float* ew2   = (const float*)d_in[23];
  const float* ea1   = (const float*)d_in[24];
  const float* ea2   = (const float*)d_in[25];
  const float* se1w1 = (const float*)d_in[26];
  const float* se1w2 = (const float*)d_in[27];
  const float* se2w1 = (const float*)d_in[28];
  const float* se2w2 = (const float*)d_in[29];

  float* ws  = (float*)d_ws;
  float* out = (float*)d_out;

  // workspace layout (float units); ~103 MB
  unsigned short* p0nm = (unsigned short*)(ws);             // motion input NHWC (later t1n)
  unsigned short* p0nv = (unsigned short*)(ws + 8388608);   // vision input NHWC (deconv2 residual)
  unsigned short* q1nb = (unsigned short*)(ws + 16777216);  // 32x64x64x128 bf16
  unsigned short* wtb  = (unsigned short*)(ws + 25165824);  // 1,105,920 bf16
  float* sm   = ws + 25718784;
  float* tn   = sm;                 // 512
  float* nb   = sm + 512;           // 8192
  float* x0   = sm + 8704;          // 9216
  float* xl   = sm + 17920;         // 102400
  float* eb   = sm + 120520;        // 28672
  float* ho   = sm + 149192;        // 18432
  float* x1   = sm + 167624;        // 18432
  float* x2   = sm + 186056;        // 9216
  float* attw = sm + 195272;        // 536
  float* pmax = sm + 195904;        // 8192 (32 n x 256 ch, fused conv2 max)

  unsigned short* v2nb = (unsigned short*)d_out;  // dead region before deconv2 rewrites it
  unsigned short* t1n = (unsigned short*)(ws);

  unsigned short* wTc1 = wtb;
  unsigned short* wTd1 = wtb + 73728;
  unsigned short* wTc2 = wtb + 147456;
  unsigned short* wTd2 = wtb + 442368;
  unsigned short* wTt1 = wtb + 737280;
  unsigned short* wTt2 = wtb + 1032192;

  // 0. fused: input prep + weight transforms + pmax zero
  k_prep_all<<<4208, 512, 0, stream>>>(mf, mp, vf, vp, p0nm, p0nv,
                                       cv1w, dc1w, cv2w, dc2w, tc1w, tc2w, wtb, pmax);

  // 1. encoder, batched (n 0-15 motion, 16-31 vision); conv2 fuses spatial max
  k_conv_mfma_b<64, 128, 64, 64, 1, true, false><<<2048, 512, 0, stream>>>(
      p0nm, p0nv, wTd1, wTc1, dc1b, cv1b, q1nb, nullptr);
  k_conv_mfma_b<128, 256, 32, 32, 2, false, true><<<1024, 512, 0, stream>>>(
      q1nb, nullptr, wTd2, wTc2, dc2b, cv2b, v2nb, pmax);
  k_ln<<<32, 256, 0, stream>>>(pmax, nb);

  // 2. node features
  k_build_x<<<2, 256, 0, stream>>>(tf, tp, nb, tn, x0);

  // 3. GNN layer 1 (OC=512)
  k_gnn_lin<<<50 * 8, 256, 0, stream>>>(x0, ea1, lin1w, xl, 256, 2048);
  k_gnn_attsm<512><<<1, 256, 0, stream>>>(xl, att1, attw);
  k_edge_agg<512><<<112, 256, 0, stream>>>(xl, attw, eb);
  k_node_agg<512><<<72, 256, 0, stream>>>(attw, eb, ew1, ho);
  k_gn_se<512, 32, false><<<1, 512, 0, stream>>>(ho, se1w1, se1w2, x1, nullptr, nullptr);

  // 4. GNN layer 2 (OC=256), observers fused into gn_se
  k_gnn_lin<<<50 * 4, 256, 0, stream>>>(x1, ea2, lin2w, xl, 512, 1024);
  k_gnn_attsm<256><<<1, 256, 0, stream>>>(xl, att2, attw);
  k_edge_agg<256><<<56, 256, 0, stream>>>(xl, attw, eb);
  k_node_agg<256><<<36, 256, 0, stream>>>(attw, eb, ew2, ho);
  k_gn_se<256, 16, true><<<1, 512, 0, stream>>>(ho, se2w1, se2w2, x2, tn, out + 16777216);

  // 5. decoder (vision halves)
  unsigned short* v2nv = v2nb + 4194304;
  unsigned short* q1nv = q1nb + 8388608;
  k_deconv_mfma<256, 128, 32, 32, 2, true, true><<<512, 256, 0, stream>>>(
      v2nv, wTt1, tc1b, q1nv, x2, t1n, nullptr);
  k_deconv_mfma<128, 64, 64, 64, 1, false, false><<<1024, 256, 0, stream>>>(
      t1n, wTt2, tc2b, p0nv, nullptr, nullptr, out);
}